// Round 3
// baseline (201.780 us; speedup 1.0000x reference)
//
#include <hip/hip_runtime.h>
#include <stdint.h>

// Toeplitz matvec = circular convolution, via batched 4096-pt FFT (radix-16,
// 3 stages). Per block: TWO real columns packed z = x[:,e0] + i*x[:,e0+1]
// (conv is real-linear -> out_e0 = Re, out_e1 = Im; no spectral unpack).
// DIF forward (digit-reversed out) -> pointwise * V (V precomputed digit-
// reversed, scaled 1/4096) -> stagewise-inverse DIT (exact inverse of each
// DIF stage, reverse order). Middle L=16 stage + pointwise + inverse L=16
// fused in registers (slots 16t..16t+15 are thread-local).
// ws: [0,32MiB) xT bf16 [8][1024][2048]; then tw float2[4096], V float2[4096].

#define B_ 8
#define N_ 2048
#define NF 4096
#define E_ 1024

#define BUFSZ (NF + (NF >> 5))          // 4224 float2 = 33 KB, swizzled
__device__ __forceinline__ int P(int n) { return n + (n >> 5); }
#define PERM(r) ((((r) & 3) << 2) | ((r) >> 2))   // DFT16 reg<->index transpose

__device__ __forceinline__ unsigned short f32_to_bf16_rne(float f) {
    union { float f; unsigned int u; } cv; cv.f = f;
    unsigned int u = cv.u;
    u += 0x7fffu + ((u >> 16) & 1u);
    return (unsigned short)(u >> 16);
}
__device__ __forceinline__ float bf16_to_f32(unsigned short u) {
    union { unsigned int u; float f; } cv; cv.u = ((unsigned int)u) << 16; return cv.f;
}
__device__ __forceinline__ void cmul(float& ar, float& ai, float br, float bi) {
    float t = ar * br - ai * bi; ai = ar * bi + ai * br; ar = t;
}

// DFT4, sg=-1 fwd (W4=-i), +1 inv. y1 = t1 + sg*i*t3, y3 = t1 - sg*i*t3.
__device__ __forceinline__ void dft4(float& x0r, float& x0i, float& x1r, float& x1i,
                                     float& x2r, float& x2i, float& x3r, float& x3i,
                                     float sg) {
    float t0r = x0r + x2r, t0i = x0i + x2i;
    float t1r = x0r - x2r, t1i = x0i - x2i;
    float t2r = x1r + x3r, t2i = x1i + x3i;
    float t3r = x1r - x3r, t3i = x1i - x3i;
    x0r = t0r + t2r; x0i = t0i + t2i;
    x2r = t0r - t2r; x2i = t0i - t2i;
    x1r = t1r - sg * t3i; x1i = t1i + sg * t3r;
    x3r = t1r + sg * t3i; x3i = t1i - sg * t3r;
}

// 16-pt DFT: n = n0+4n1, k = k1+4k2. Inner DFT4 over n1, twiddle W16^(n0*k1),
// outer DFT4 over n0. Result X[k1+4k2] lands in reg slot 4k1+k2 (= PERM).
template<int SG>
__device__ __forceinline__ void dft16(float* xr, float* xi) {
    const float sg = (float)SG;
#pragma unroll
    for (int n0 = 0; n0 < 4; ++n0)
        dft4(xr[n0], xi[n0], xr[n0 + 4], xi[n0 + 4],
             xr[n0 + 8], xi[n0 + 8], xr[n0 + 12], xi[n0 + 12], sg);
    const float C1 = 0.923879532511286756f;   // cos(pi/8)
    const float S1 = 0.382683432365089772f;   // sin(pi/8)
    const float H  = 0.707106781186547524f;
    // W16^m = (cos th, sg*sin th), th = 2*pi*m/16, at reg slot n0+4k1
    cmul(xr[5],  xi[5],  C1,  sg * S1);   // m=1
    cmul(xr[9],  xi[9],  H,   sg * H);    // m=2
    cmul(xr[13], xi[13], S1,  sg * C1);   // m=3
    cmul(xr[6],  xi[6],  H,   sg * H);    // m=2
    cmul(xr[10], xi[10], 0.f, sg);        // m=4
    cmul(xr[14], xi[14], -H,  sg * H);    // m=6
    cmul(xr[7],  xi[7],  S1,  sg * C1);   // m=3
    cmul(xr[11], xi[11], -H,  sg * H);    // m=6
    cmul(xr[15], xi[15], -C1, -sg * S1);  // m=9
#pragma unroll
    for (int k1 = 0; k1 < 4; ++k1)
        dft4(xr[4 * k1], xi[4 * k1], xr[4 * k1 + 1], xi[4 * k1 + 1],
             xr[4 * k1 + 2], xi[4 * k1 + 2], xr[4 * k1 + 3], xi[4 * k1 + 3], sg);
}

// One in-place radix-16 stage. Fwd (DIF): DFT16 then post-twiddle W_L^(j*r).
// Inv (DIT): pre-twiddle conj(W_L^(j*r)) then inverse DFT16. Same slots.
template<int INV, int L>
__device__ __forceinline__ void fft_stage(float2* buf, const float2* __restrict__ tw2, int t) {
    constexpr int Lq = L / 16;
    int g = t / Lq;
    int j = t - g * Lq;
    int base = g * L + j;
    float xr[16], xi[16];
#pragma unroll
    for (int r = 0; r < 16; ++r) {
        float2 v = buf[P(base + r * Lq)];
        xr[r] = v.x; xi[r] = v.y;
    }
    float2 w1 = tw2[j * (NF / L)];
    float w1r = w1.x, w1i = INV ? -w1.y : w1.y;
    if (INV) {
        float wr = 1.f, wi = 0.f;
#pragma unroll
        for (int r = 1; r < 16; ++r) { cmul(wr, wi, w1r, w1i); cmul(xr[r], xi[r], wr, wi); }
        dft16<1>(xr, xi);
#pragma unroll
        for (int r = 0; r < 16; ++r) {
            float2 v; v.x = xr[PERM(r)]; v.y = xi[PERM(r)];
            buf[P(base + r * Lq)] = v;
        }
    } else {
        dft16<-1>(xr, xi);
        { float2 v; v.x = xr[0]; v.y = xi[0]; buf[P(base)] = v; }
        float wr = 1.f, wi = 0.f;
#pragma unroll
        for (int r = 1; r < 16; ++r) {
            cmul(wr, wi, w1r, w1i);
            float yr = xr[PERM(r)], yi = xi[PERM(r)];
            cmul(yr, yi, wr, wi);
            float2 v; v.x = yr; v.y = yi;
            buf[P(base + r * Lq)] = v;
        }
    }
}

// ---------------- twiddle table: tw[k] = e^(-2*pi*i*k/4096) -----------------
__global__ __launch_bounds__(256) void build_tw(float2* tw2) {
    int k = blockIdx.x * 256 + threadIdx.x;
    double th = -6.283185307179586476925286766559 * (double)k / 4096.0;
    float2 v; v.x = (float)cos(th); v.y = (float)sin(th);
    tw2[k] = v;
}

// ---------------- V = DIF(a)/4096, stored in raw (digit-reversed) slots -----
__global__ __launch_bounds__(256) void build_V(const float* __restrict__ pos,
                                               const float* __restrict__ zero,
                                               const float* __restrict__ neg,
                                               const float2* __restrict__ tw2,
                                               float2* __restrict__ V2) {
    __shared__ float2 buf[BUFSZ];
    int t = threadIdx.x;
#pragma unroll
    for (int it = 0; it < 16; ++it) {
        int n = t + 256 * it;
        float v;
        if (n == 0) v = zero[0];
        else if (n < N_) v = pos[n - 1];
        else if (n == N_) v = zero[0];
        else v = neg[n - (N_ + 1)];
        float2 c; c.x = v; c.y = 0.f;
        buf[P(n)] = c;
    }
    __syncthreads();
    fft_stage<0, 4096>(buf, tw2, t); __syncthreads();
    fft_stage<0, 256>(buf, tw2, t);  __syncthreads();
    fft_stage<0, 16>(buf, tw2, t);   __syncthreads();
    const float s = 1.f / (float)NF;
#pragma unroll
    for (int it = 0; it < 16; ++it) {
        int n = t + 256 * it;
        float2 c = buf[P(n)];
        c.x *= s; c.y *= s;
        V2[n] = c;
    }
}

// ---------------- x [b][j][e] fp32 -> xT [b][e][j] bf16 (R2, verified) ------
__global__ __launch_bounds__(256) void transpose_x(const float* __restrict__ x,
                                                   unsigned short* __restrict__ xT) {
    __shared__ float tile[64][66];
    int b  = blockIdx.z;
    int j0 = blockIdx.y * 64;
    int e0 = blockIdx.x * 64;
    int t  = threadIdx.x;

    int e4 = t & 15, jr = t >> 4;
#pragma unroll
    for (int it = 0; it < 4; ++it) {
        int j = jr + it * 16;
        const float4 v = *(const float4*)(x + ((size_t)(b * N_ + j0 + j) * E_) + e0 + e4 * 4);
        tile[e4 * 4 + 0][j] = v.x;
        tile[e4 * 4 + 1][j] = v.y;
        tile[e4 * 4 + 2][j] = v.z;
        tile[e4 * 4 + 3][j] = v.w;
    }
    __syncthreads();
    int j2 = (t & 31) * 2, er = t >> 5;
#pragma unroll
    for (int it = 0; it < 8; ++it) {
        int e = er + it * 8;
        float2 v = *(const float2*)&tile[e][j2];
        union { unsigned short s[2]; unsigned int u; } pk;
        pk.s[0] = f32_to_bf16_rne(v.x);
        pk.s[1] = f32_to_bf16_rne(v.y);
        *(unsigned int*)(xT + ((size_t)(b * E_ + e0 + e)) * N_ + j0 + j2) = pk.u;
    }
}

// ---------------- main: FFT-conv of one column pair per block ---------------
__global__ __launch_bounds__(256) void fft_conv(const unsigned short* __restrict__ xT,
                                                const float2* __restrict__ tw2,
                                                const float2* __restrict__ V2,
                                                float* __restrict__ out) {
    __shared__ float2 buf[BUFSZ];
    int t = threadIdx.x;
    int bid = blockIdx.x;
    // XCD swizzle: e-adjacent blocks (sharing output cache lines) on one XCD
    int xcd = bid & 7;
    int q = bid >> 3;            // 0..511
    int b = q >> 6;              // 0..7
    int ep = xcd * 64 + (q & 63);
    int e0 = ep * 2;

    // load: z[n] = x[b][n][e0] + i*x[b][n][e0+1], zero-pad to 4096
    const unsigned short* r0 = xT + ((size_t)(b * E_ + e0)) * N_;
    uint4 u0 = ((const uint4*)r0)[t];
    uint4 u1 = ((const uint4*)(r0 + N_))[t];
    unsigned int a0[4] = { u0.x, u0.y, u0.z, u0.w };
    unsigned int a1[4] = { u1.x, u1.y, u1.z, u1.w };
#pragma unroll
    for (int i = 0; i < 4; ++i) {
        int n = 8 * t + 2 * i;
        float2 c0; c0.x = bf16_to_f32((unsigned short)(a0[i] & 0xffff));
        c0.y = bf16_to_f32((unsigned short)(a1[i] & 0xffff));
        buf[P(n)] = c0;
        float2 c1; c1.x = bf16_to_f32((unsigned short)(a0[i] >> 16));
        c1.y = bf16_to_f32((unsigned short)(a1[i] >> 16));
        buf[P(n + 1)] = c1;
    }
#pragma unroll
    for (int it = 0; it < 8; ++it) {
        int n = N_ + t + 256 * it;
        float2 z; z.x = 0.f; z.y = 0.f;
        buf[P(n)] = z;
    }
    __syncthreads();
    fft_stage<0, 4096>(buf, tw2, t); __syncthreads();
    fft_stage<0, 256>(buf, tw2, t);  __syncthreads();
    // fused: fwd L=16 (j=0, no twiddle) + pointwise*V + inv L=16, in registers
    {
        int base = 16 * t;
        float xr[16], xi[16];
#pragma unroll
        for (int r = 0; r < 16; ++r) {
            float2 v = buf[P(base + r)];
            xr[r] = v.x; xi[r] = v.y;
        }
        dft16<-1>(xr, xi);
        float yr[16], yi[16];
#pragma unroll
        for (int r = 0; r < 16; ++r) {
            float2 vv = V2[base + r];
            float ar = xr[PERM(r)], ai = xi[PERM(r)];
            yr[r] = ar * vv.x - ai * vv.y;
            yi[r] = ar * vv.y + ai * vv.x;
        }
        dft16<1>(yr, yi);
#pragma unroll
        for (int r = 0; r < 16; ++r) {
            float2 v; v.x = yr[PERM(r)]; v.y = yi[PERM(r)];
            buf[P(base + r)] = v;
        }
    }
    __syncthreads();
    fft_stage<1, 256>(buf, tw2, t);  __syncthreads();
    fft_stage<1, 4096>(buf, tw2, t); __syncthreads();

    // out[b][k][e0] = Re, [e0+1] = Im
    float* ob = out + ((size_t)b * N_) * E_ + e0;
#pragma unroll
    for (int it = 0; it < 8; ++it) {
        int k = t + 256 * it;
        float2 v = buf[P(k)];
        *(float2*)(ob + (size_t)k * E_) = v;
    }
}

// ---------------- fallback (ws too small): direct fp32 dot ------------------
__global__ __launch_bounds__(256) void naive_toep(const float* __restrict__ x,
                                                  const float* __restrict__ pos,
                                                  const float* __restrict__ zero,
                                                  const float* __restrict__ neg,
                                                  float* __restrict__ out) {
    int bid = blockIdx.x;
    int e   = (bid & 3) * 256 + threadIdx.x;
    int k   = (bid >> 2) & (N_ - 1);
    int b   = bid >> 13;
    float zv = zero[0];
    float acc = 0.f;
    const float* xb = x + (size_t)b * N_ * E_ + e;
    for (int j = 0; j < N_; ++j) {
        float c = (j < k) ? pos[k - j - 1] : (j == k) ? zv : neg[N_ - 1 - j + k];
        acc += c * xb[(size_t)j * E_];
    }
    out[((size_t)(b * N_ + k)) * E_ + e] = acc;
}

extern "C" void kernel_launch(void* const* d_in, const int* in_sizes, int n_in,
                              void* d_out, int out_size, void* d_ws, size_t ws_size,
                              hipStream_t stream) {
    const float* x    = (const float*)d_in[0];
    const float* pos  = (const float*)d_in[1];
    const float* zero = (const float*)d_in[2];
    const float* neg  = (const float*)d_in[3];
    float* out = (float*)d_out;

    const size_t needX = (size_t)B_ * E_ * N_ * sizeof(unsigned short);   // 32 MiB
    const size_t need  = needX + 2 * (size_t)NF * sizeof(float2);         // + 64 KiB
    if (ws_size >= need) {
        unsigned short* xT = (unsigned short*)d_ws;
        float2* tw2 = (float2*)((char*)d_ws + needX);
        float2* V2  = tw2 + NF;
        build_tw<<<16, 256, 0, stream>>>(tw2);
        transpose_x<<<dim3(16, 32, 8), 256, 0, stream>>>(x, xT);
        build_V<<<1, 256, 0, stream>>>(pos, zero, neg, tw2, V2);
        fft_conv<<<4096, 256, 0, stream>>>(xT, tw2, V2, out);
    } else {
        naive_toep<<<65536, 256, 0, stream>>>(x, pos, zero, neg, out);
    }
}